// Round 1
// 277.954 us; speedup vs baseline: 1.1182x; 1.1182x over previous
//
#include <hip/hip_runtime.h>
#include <hip/hip_bf16.h>

#define BB 16
#define LL 4096
#define PDIM 512
#define HH 256
#define HALFD 128
#define MT 32      // tokens per proj block
#define NBUCK 257  // bucket 0 = exact-zero keys (prefix tokens); 1..256 = floor(noise*256)

typedef short bf16x8 __attribute__((ext_vector_type(8)));   // 8 bf16 in 4 VGPRs
typedef float f32x4 __attribute__((ext_vector_type(4)));

__device__ __forceinline__ unsigned short f2bf(float f) {
  unsigned x = __float_as_uint(f);
  unsigned r = (x + 0x7FFFu + ((x >> 16) & 1u)) >> 16;
  return (unsigned short)r;
}

// ---------------- fused: per-row bucket-rank + finalize (blocks 0..15),
//                  W->bf16 (blocks 16..143), fs MLP (blocks 144..159) ----------------
// Rank semantics (matches stable argsort of (noise_bits, j)):
//   invalid (j>=eff): key=(+inf,j) -> rank = eff + (j-eff) = j  (analytic, no sort)
//   valid: bucket by monotone map of key bits; rank = bucket_start + #smaller-in-bucket
__global__ __launch_bounds__(1024) void sort_prep_kernel(
    const int* __restrict__ sample_ids, const int* __restrict__ eff_lens,
    const float* __restrict__ noise, float* __restrict__ out_mae,
    float* __restrict__ out_restore, float* __restrict__ out_unmask,
    int* __restrict__ keep_idx, int* __restrict__ lk_arr,
    const float* __restrict__ W, unsigned short* __restrict__ Wbf,
    const float* __restrict__ fs, const float* __restrict__ w1,
    const float* __restrict__ b1, const float* __restrict__ w2,
    const float* __restrict__ b2, float* __restrict__ fs_emb) {
  __shared__ __align__(16) unsigned long long store[LL];  // 32 KB bucketed keys
  __shared__ int hist[NBUCK], cnt[NBUCK], bstart[NBUCK], bcur[NBUCK];
  __shared__ int wsum[16];
  __shared__ int lksh;
  __shared__ float tf[HH];
  __shared__ float hidv[HH];

  const int tid = threadIdx.x;

  if (blockIdx.x >= 16) {
    const int blk = blockIdx.x - 16;
    if (blk < 128) {  // W -> bf16: 128 blocks x 1024 = 131072 elements
      const int idx = blk * 1024 + tid;
      Wbf[idx] = f2bf(W[idx]);
      return;
    }
    // fs MLP: one block per batch row, first 256 threads active
    const int b = blk - 128, h = tid;
    const float fv = fs[b];
    if (h < HH) {
      int i = h & (HALFD - 1);
      float freq = expf(-9.210340371976184f * (float)i / 128.0f);
      float arg = fv * freq;
      tf[h] = (h < HALFD) ? cosf(arg) : sinf(arg);
    }
    __syncthreads();
    if (h < HH) {
      float acc = b1[h];
      const float* wr = w1 + (size_t)h * HH;
      for (int k = 0; k < HH; k += 4) {
        float4 w4 = *reinterpret_cast<const float4*>(&wr[k]);
        acc += tf[k] * w4.x + tf[k + 1] * w4.y + tf[k + 2] * w4.z + tf[k + 3] * w4.w;
      }
      hidv[h] = acc / (1.0f + expf(-acc));
    }
    __syncthreads();
    if (h < HH) {
      float acc2 = b2[h];
      const float* wr2 = w2 + (size_t)h * HH;
      for (int k = 0; k < HH; k += 4) {
        float4 w4 = *reinterpret_cast<const float4*>(&wr2[k]);
        acc2 += hidv[k] * w4.x + hidv[k + 1] * w4.y + hidv[k + 2] * w4.z + hidv[k + 3] * w4.w;
      }
      fs_emb[b * HH + h] = acc2;
    }
    return;
  }

  // ---------------- sort + finalize for row b ----------------
  const int b = blockIdx.x;
  const int wid = tid >> 6, lane = tid & 63;
  const int eff = eff_lens[b];
  const int* sid = sample_ids + (size_t)b * LL;
  const int base = tid * 4;

  int4 sv = *reinterpret_cast<const int4*>(&sid[base]);
  float4 nv = *reinterpret_cast<const float4*>(&noise[(size_t)b * LL + base]);
  const int sm1 = (base >= 1) ? sid[base - 1] : -1;
  const int sm2 = (base >= 2) ? sid[base - 2] : -1;
  const int svA[4] = {sv.x, sv.y, sv.z, sv.w};
  const float nvA[4] = {nv.x, nv.y, nv.z, nv.w};

  unsigned vbq[4];
  int pbq[4];
  bool invq[4];
  int segsum = 0;
#pragma unroll
  for (int q = 0; q < 4; ++q) {
    const int j = base + q;
    const int s = svA[q];
    const int sp = (q >= 1) ? svA[q - 1] : sm1;
    const int spp = (q >= 2) ? svA[q - 2] : ((q == 1) ? sm1 : sm2);
    const bool valid = j < eff;
    const bool segs = valid && (s != sp);
    const bool fst = valid && (j > 0) && (sp != spp);
    segsum += segs ? 1 : 0;
    invq[q] = !valid;
    unsigned vb = (segs || fst) ? 0u : __float_as_uint(nvA[q]);
    vbq[q] = vb;
    // monotone bucket map: exact-zero keys -> 0; else 1+floor(v*256) in [1,256]
    pbq[q] = (vb == 0u) ? 0 : (1 + (int)(__uint_as_float(vb) * 256.0f));
  }

  // histogram
  if (tid < NBUCK) hist[tid] = 0;
  __syncthreads();
#pragma unroll
  for (int q = 0; q < 4; ++q)
    if (!invq[q]) atomicAdd(&hist[pbq[q]], 1);
  __syncthreads();
  if (tid < NBUCK) cnt[tid] = hist[tid];
  __syncthreads();
  // inclusive Hillis-Steele scan over 257 buckets
  for (int off = 1; off < NBUCK; off <<= 1) {
    int v = 0;
    if (tid < NBUCK && tid >= off) v = hist[tid - off];
    __syncthreads();
    if (tid < NBUCK) hist[tid] += v;
    __syncthreads();
  }
  if (tid < NBUCK) {
    const int st = hist[tid] - cnt[tid];  // exclusive start
    bstart[tid] = st;
    bcur[tid] = st;
  }
  __syncthreads();
  // scatter valid keys into bucketed storage (order within bucket irrelevant)
#pragma unroll
  for (int q = 0; q < 4; ++q)
    if (!invq[q]) {
      const int slot = atomicAdd(&bcur[pbq[q]], 1);
      store[slot] = (((unsigned long long)vbq[q]) << 32) | (unsigned)(base + q);
    }
  __syncthreads();

  // rank: bucket start + count of strictly-smaller keys in bucket (keys unique via j)
  int r4[4];
#pragma unroll
  for (int q = 0; q < 4; ++q) {
    const int j = base + q;
    if (invq[q]) {
      r4[q] = j;
      continue;
    }
    const int pb = pbq[q];
    const int s0 = bstart[pb], c = cnt[pb];
    const unsigned long long mykey = (((unsigned long long)vbq[q]) << 32) | (unsigned)j;
    int cless = 0;
    for (int t = 0; t < c; ++t) cless += (store[s0 + t] < mykey) ? 1 : 0;
    r4[q] = s0 + cless;
  }

  // ---- ns -> len_keep ----
  int local_ns = segsum;
#pragma unroll
  for (int off = 32; off > 0; off >>= 1) local_ns += __shfl_down(local_ns, off);
  if (lane == 0) wsum[wid] = local_ns;
  __syncthreads();
  if (wid == 0) {
    int v = (lane < 16) ? wsum[lane] : 0;
#pragma unroll
    for (int off = 32; off > 0; off >>= 1) v += __shfl_down(v, off);
    if (lane == 0) {
      const int ns = v;
      lksh = 2 * ns + ((eff - 2 * ns) >> 2);  // exact trunc
    }
  }
  __syncthreads();
  const int lk = lksh;

  // ---- kept flags + exclusive prefix via shfl scan (verified structure) ----
  int c4[4], cntk = 0;
#pragma unroll
  for (int q = 0; q < 4; ++q) {
    c4[q] = (r4[q] < lk) ? 1 : 0;
    cntk += c4[q];
  }
  int incl = cntk;
#pragma unroll
  for (int off = 1; off < 64; off <<= 1) {
    int v = __shfl_up(incl, off);
    if (lane >= off) incl += v;
  }
  if (lane == 63) wsum[wid] = incl;
  __syncthreads();
  if (wid == 0) {
    int s = (lane < 16) ? wsum[lane] : 0;
#pragma unroll
    for (int off = 1; off < 16; off <<= 1) {
      int v = __shfl_up(s, off);
      if (lane >= off) s += v;
    }
    if (lane < 16) wsum[lane] = s;  // inclusive wave sums
  }
  __syncthreads();
  int run = ((wid > 0) ? wsum[wid - 1] : 0) + incl - cntk;  // exclusive prefix

  float4 rst, mmk;
  float* rp = &rst.x;
  float* mp = &mmk.x;
#pragma unroll
  for (int q = 0; q < 4; ++q) {
    const int j = base + q;
    int r;
    if (c4[q]) {
      r = run;
      keep_idx[b * LL + run] = j;
      out_unmask[(size_t)b * LL + run] = (float)svA[q];
      run++;
    } else {
      r = r4[q];
    }
    rp[q] = (float)r;
    mp[q] = (r >= lk && r < eff) ? 1.0f : 0.0f;
  }
  *reinterpret_cast<float4*>(out_restore + (size_t)b * LL + base) = rst;
  *reinterpret_cast<float4*>(out_mae + (size_t)b * LL + base) = mmk;

  for (int p = tid; p < LL; p += 1024)
    if (p >= lk) out_unmask[(size_t)b * LL + p] = -1.0f;
  if (tid == 0) lk_arr[b] = lk;
}

// ---------------- proj: MFMA bf16 GEMM, 32 tokens x 256 h x K=512 per block ----------------
__global__ __launch_bounds__(256) void proj_kernel(
    const float* __restrict__ patches, const unsigned short* __restrict__ Wbf,
    const float* __restrict__ bias, const float* __restrict__ pos,
    const float* __restrict__ fs_emb, const int* __restrict__ keep_idx,
    const int* __restrict__ lk_arr, float* __restrict__ out0) {
  const int tile = blockIdx.x, b = blockIdx.y, tid = threadIdx.x;
  const int p0 = tile * MT;
  int lk = lk_arr[b];
  lk = lk < 0 ? 0 : (lk > LL ? LL : lk);
  float* outB = out0 + ((size_t)b * LL + p0) * HH;
  int nt = lk - p0;
  nt = nt > MT ? MT : nt;

  if (nt <= 0) {  // pure zero-fill tile
    float4 z = make_float4(0.f, 0.f, 0.f, 0.f);
    float4* o4 = reinterpret_cast<float4*>(outB);
#pragma unroll
    for (int i = 0; i < MT * HH / 4 / 256; ++i)
      o4[i * 256 + tid] = z;
    return;
  }

  __shared__ __align__(16) unsigned short pA[MT * 520];  // [t][k] bf16, stride 520
  __shared__ int idxs[MT];
  if (tid < MT) idxs[tid] = (tid < nt) ? (keep_idx[b * LL + p0 + tid] & (LL - 1)) : 0;
  __syncthreads();

  {  // stage gathered patch rows as bf16: 8 threads per row, 64 k each
    const int r = tid >> 3, kc = (tid & 7) * 64;
    const float* prow = patches + ((size_t)b * LL + (size_t)idxs[r]) * PDIM + kc;
#pragma unroll
    for (int i = 0; i < 16; ++i) {
      float4 v = reinterpret_cast<const float4*>(prow)[i];
      ushort4 u = make_ushort4(f2bf(v.x), f2bf(v.y), f2bf(v.z), f2bf(v.w));
      *reinterpret_cast<ushort4*>(&pA[r * 520 + kc + i * 4]) = u;
    }
  }
  __syncthreads();

  const int lane = tid & 63, w = tid >> 6;
  const int li = lane & 15, q = lane >> 4;
  f32x4 zero4 = {0.f, 0.f, 0.f, 0.f};
  f32x4 acc[2][4];
#pragma unroll
  for (int m = 0; m < 2; ++m)
#pragma unroll
    for (int n = 0; n < 4; ++n) acc[m][n] = zero4;

#pragma unroll 2
  for (int k0 = 0; k0 < PDIM; k0 += 32) {
    bf16x8 a0 = *reinterpret_cast<const bf16x8*>(&pA[li * 520 + k0 + q * 8]);
    bf16x8 a1 = *reinterpret_cast<const bf16x8*>(&pA[(16 + li) * 520 + k0 + q * 8]);
#pragma unroll
    for (int n = 0; n < 4; ++n) {
      bf16x8 bf = *reinterpret_cast<const bf16x8*>(
          &Wbf[(size_t)(w * 64 + n * 16 + li) * PDIM + k0 + q * 8]);
      acc[0][n] = __builtin_amdgcn_mfma_f32_16x16x32_bf16(a0, bf, acc[0][n], 0, 0, 0);
      acc[1][n] = __builtin_amdgcn_mfma_f32_16x16x32_bf16(a1, bf, acc[1][n], 0, 0, 0);
    }
  }

  // epilogue: D[row=q*4+r][col=li] (+ bias + pos[idx] + fs_emb), rows >= lk -> 0
#pragma unroll
  for (int m = 0; m < 2; ++m) {
#pragma unroll
    for (int n = 0; n < 4; ++n) {
      const int col = w * 64 + n * 16 + li;
      const float bv = bias[col] + fs_emb[b * HH + col];
#pragma unroll
      for (int rr = 0; rr < 4; ++rr) {
        const int trow = m * 16 + q * 4 + rr;
        float val = 0.f;
        if (p0 + trow < lk)
          val = acc[m][n][rr] + bv + pos[(size_t)idxs[trow] * HH + col];
        outB[(size_t)trow * HH + col] = val;
      }
    }
  }
}

extern "C" void kernel_launch(void* const* d_in, const int* in_sizes, int n_in,
                              void* d_out, int out_size, void* d_ws, size_t ws_size,
                              hipStream_t stream) {
  const float* patches = (const float*)d_in[0];
  const int* sample_ids = (const int*)d_in[1];
  const int* eff = (const int*)d_in[2];
  const float* noise = (const float*)d_in[3];
  const float* fs = (const float*)d_in[4];
  const float* W = (const float*)d_in[5];
  const float* bias = (const float*)d_in[6];
  const float* pos = (const float*)d_in[7];
  const float* w1 = (const float*)d_in[8];
  const float* b1 = (const float*)d_in[9];
  const float* w2 = (const float*)d_in[10];
  const float* b2 = (const float*)d_in[11];

  float* out0 = (float*)d_out;                            // seq_unmasked fp32 [16,4096,256]
  float* out_mae = out0 + (size_t)BB * LL * HH;           // mae_mask   [16,4096]
  float* out_restore = out_mae + (size_t)BB * LL;         // ids_restore[16,4096]
  float* out_unmask = out_restore + (size_t)BB * LL;      // unmask_ids [16,4096]

  char* ws = (char*)d_ws;
  unsigned short* Wbf = (unsigned short*)ws;     // 262144 B (bf16 [256][512])
  float* fs_emb = (float*)(ws + 262144);         // 16384 B
  int* keep_idx = (int*)(ws + 278528);           // 262144 B
  int* lk_arr = (int*)(ws + 540672);             // 64 B
  if (ws_size < 540736) return;

  // launch 1: 16 sort+finalize blocks + 128 W-convert blocks + 16 fs-MLP blocks
  sort_prep_kernel<<<160, 1024, 0, stream>>>(sample_ids, eff, noise, out_mae,
                                             out_restore, out_unmask, keep_idx,
                                             lk_arr, W, Wbf, fs, w1, b1, w2, b2,
                                             fs_emb);
  // launch 2: projection + epilogue
  proj_kernel<<<dim3(LL / MT, BB), 256, 0, stream>>>(patches, Wbf, bias, pos,
                                                     fs_emb, keep_idx, lk_arr, out0);
}

// Round 2
// 268.198 us; speedup vs baseline: 1.1589x; 1.0364x over previous
//
#include <hip/hip_runtime.h>
#include <hip/hip_bf16.h>

#define BB 16
#define LL 4096
#define PDIM 512
#define HH 256
#define HALFD 128
#define MT 32      // tokens per proj block
#define NBUCK 257  // bucket 0 = exact-zero keys (prefix tokens); 1..256 = floor(noise*256)
// lk = 2*ns + (eff-2*ns)>>2 with eff<=4095, ns<=8  =>  lk <= 1035 < 1088.
// Tokens >= 1088 (tiles >= 34) of out0 are statically zero -> filled in launch 1.
#define PROJ_TILES 34
#define FILL_BLOCKS 512  // 32 per batch row

typedef short bf16x8 __attribute__((ext_vector_type(8)));   // 8 bf16 in 4 VGPRs
typedef float f32x4 __attribute__((ext_vector_type(4)));

__device__ __forceinline__ unsigned short f2bf(float f) {
  unsigned x = __float_as_uint(f);
  unsigned r = (x + 0x7FFFu + ((x >> 16) & 1u)) >> 16;
  return (unsigned short)r;
}

// ---------------- fused launch 1:
//   blocks   0..15  : per-row bucket-rank + finalize
//   blocks  16..143 : W -> bf16
//   blocks 144..159 : fs MLP
//   blocks 160..671 : static zero-fill of out0 tokens 1088..4095 (overlaps sort)
__global__ __launch_bounds__(1024) void sort_prep_kernel(
    const int* __restrict__ sample_ids, const int* __restrict__ eff_lens,
    const float* __restrict__ noise, float* __restrict__ out_mae,
    float* __restrict__ out_restore, float* __restrict__ out_unmask,
    int* __restrict__ keep_idx, int* __restrict__ lk_arr,
    const float* __restrict__ W, unsigned short* __restrict__ Wbf,
    const float* __restrict__ fs, const float* __restrict__ w1,
    const float* __restrict__ b1, const float* __restrict__ w2,
    const float* __restrict__ b2, float* __restrict__ fs_emb,
    float* __restrict__ out0) {
  __shared__ __align__(16) unsigned long long store[LL];  // 32 KB bucketed keys
  __shared__ int hist[NBUCK], cnt[NBUCK], bstart[NBUCK], bcur[NBUCK];
  __shared__ int wsum[16];
  __shared__ int lksh;
  __shared__ float tf[HH];
  __shared__ float hidv[HH];

  const int tid = threadIdx.x;

  if (blockIdx.x >= 160) {
    // static zero-fill: tokens 1088..4095 of every row are always beyond len_keep
    const int fb = blockIdx.x - 160;  // 0..511
    const int row = fb >> 5;          // 0..15
    const int chunk = fb & 31;        // 0..31
    float4* dst = reinterpret_cast<float4*>(out0 + ((size_t)row * LL + 1088) * HH);
    const int start = chunk * 6016;   // 32 * 6016 = (4096-1088)*256/4 per row
    const float4 z = make_float4(0.f, 0.f, 0.f, 0.f);
#pragma unroll
    for (int k = 0; k < 6; ++k) {
      const int i = k * 1024 + tid;
      if (i < 6016) dst[start + i] = z;
    }
    return;
  }

  if (blockIdx.x >= 16) {
    const int blk = blockIdx.x - 16;
    if (blk < 128) {  // W -> bf16: 128 blocks x 1024 = 131072 elements
      const int idx = blk * 1024 + tid;
      Wbf[idx] = f2bf(W[idx]);
      return;
    }
    // fs MLP: one block per batch row, first 256 threads active
    const int b = blk - 128, h = tid;
    const float fv = fs[b];
    if (h < HH) {
      int i = h & (HALFD - 1);
      float freq = expf(-9.210340371976184f * (float)i / 128.0f);
      float arg = fv * freq;
      tf[h] = (h < HALFD) ? cosf(arg) : sinf(arg);
    }
    __syncthreads();
    if (h < HH) {
      float acc = b1[h];
      const float* wr = w1 + (size_t)h * HH;
      for (int k = 0; k < HH; k += 4) {
        float4 w4 = *reinterpret_cast<const float4*>(&wr[k]);
        acc += tf[k] * w4.x + tf[k + 1] * w4.y + tf[k + 2] * w4.z + tf[k + 3] * w4.w;
      }
      hidv[h] = acc / (1.0f + expf(-acc));
    }
    __syncthreads();
    if (h < HH) {
      float acc2 = b2[h];
      const float* wr2 = w2 + (size_t)h * HH;
      for (int k = 0; k < HH; k += 4) {
        float4 w4 = *reinterpret_cast<const float4*>(&wr2[k]);
        acc2 += hidv[k] * w4.x + hidv[k + 1] * w4.y + hidv[k + 2] * w4.z + hidv[k + 3] * w4.w;
      }
      fs_emb[b * HH + h] = acc2;
    }
    return;
  }

  // ---------------- sort + finalize for row b ----------------
  const int b = blockIdx.x;
  const int wid = tid >> 6, lane = tid & 63;
  const int eff = eff_lens[b];
  const int* sid = sample_ids + (size_t)b * LL;
  const int base = tid * 4;

  int4 sv = *reinterpret_cast<const int4*>(&sid[base]);
  float4 nv = *reinterpret_cast<const float4*>(&noise[(size_t)b * LL + base]);
  const int sm1 = (base >= 1) ? sid[base - 1] : -1;
  const int sm2 = (base >= 2) ? sid[base - 2] : -1;
  const int svA[4] = {sv.x, sv.y, sv.z, sv.w};
  const float nvA[4] = {nv.x, nv.y, nv.z, nv.w};

  unsigned vbq[4];
  int pbq[4];
  bool invq[4];
  int segsum = 0;
#pragma unroll
  for (int q = 0; q < 4; ++q) {
    const int j = base + q;
    const int s = svA[q];
    const int sp = (q >= 1) ? svA[q - 1] : sm1;
    const int spp = (q >= 2) ? svA[q - 2] : ((q == 1) ? sm1 : sm2);
    const bool valid = j < eff;
    const bool segs = valid && (s != sp);
    const bool fst = valid && (j > 0) && (sp != spp);
    segsum += segs ? 1 : 0;
    invq[q] = !valid;
    unsigned vb = (segs || fst) ? 0u : __float_as_uint(nvA[q]);
    vbq[q] = vb;
    // monotone bucket map: exact-zero keys -> 0; else 1+floor(v*256) in [1,256]
    pbq[q] = (vb == 0u) ? 0 : (1 + (int)(__uint_as_float(vb) * 256.0f));
  }

  // histogram
  if (tid < NBUCK) hist[tid] = 0;
  __syncthreads();
#pragma unroll
  for (int q = 0; q < 4; ++q)
    if (!invq[q]) atomicAdd(&hist[pbq[q]], 1);
  __syncthreads();
  if (tid < NBUCK) cnt[tid] = hist[tid];
  __syncthreads();
  // inclusive Hillis-Steele scan over 257 buckets
  for (int off = 1; off < NBUCK; off <<= 1) {
    int v = 0;
    if (tid < NBUCK && tid >= off) v = hist[tid - off];
    __syncthreads();
    if (tid < NBUCK) hist[tid] += v;
    __syncthreads();
  }
  if (tid < NBUCK) {
    const int st = hist[tid] - cnt[tid];  // exclusive start
    bstart[tid] = st;
    bcur[tid] = st;
  }
  __syncthreads();
  // scatter valid keys into bucketed storage (order within bucket irrelevant)
#pragma unroll
  for (int q = 0; q < 4; ++q)
    if (!invq[q]) {
      const int slot = atomicAdd(&bcur[pbq[q]], 1);
      store[slot] = (((unsigned long long)vbq[q]) << 32) | (unsigned)(base + q);
    }
  __syncthreads();

  // rank: bucket start + count of strictly-smaller keys in bucket (keys unique via j)
  int r4[4];
#pragma unroll
  for (int q = 0; q < 4; ++q) {
    const int j = base + q;
    if (invq[q]) {
      r4[q] = j;
      continue;
    }
    const int pb = pbq[q];
    const int s0 = bstart[pb], c = cnt[pb];
    const unsigned long long mykey = (((unsigned long long)vbq[q]) << 32) | (unsigned)j;
    int cless = 0;
    for (int t = 0; t < c; ++t) cless += (store[s0 + t] < mykey) ? 1 : 0;
    r4[q] = s0 + cless;
  }

  // ---- ns -> len_keep ----
  int local_ns = segsum;
#pragma unroll
  for (int off = 32; off > 0; off >>= 1) local_ns += __shfl_down(local_ns, off);
  if (lane == 0) wsum[wid] = local_ns;
  __syncthreads();
  if (wid == 0) {
    int v = (lane < 16) ? wsum[lane] : 0;
#pragma unroll
    for (int off = 32; off > 0; off >>= 1) v += __shfl_down(v, off);
    if (lane == 0) {
      const int ns = v;
      lksh = 2 * ns + ((eff - 2 * ns) >> 2);  // exact trunc
    }
  }
  __syncthreads();
  const int lk = lksh;

  // ---- kept flags + exclusive prefix via shfl scan (verified structure) ----
  int c4[4], cntk = 0;
#pragma unroll
  for (int q = 0; q < 4; ++q) {
    c4[q] = (r4[q] < lk) ? 1 : 0;
    cntk += c4[q];
  }
  int incl = cntk;
#pragma unroll
  for (int off = 1; off < 64; off <<= 1) {
    int v = __shfl_up(incl, off);
    if (lane >= off) incl += v;
  }
  if (lane == 63) wsum[wid] = incl;
  __syncthreads();
  if (wid == 0) {
    int s = (lane < 16) ? wsum[lane] : 0;
#pragma unroll
    for (int off = 1; off < 16; off <<= 1) {
      int v = __shfl_up(s, off);
      if (lane >= off) s += v;
    }
    if (lane < 16) wsum[lane] = s;  // inclusive wave sums
  }
  __syncthreads();
  int run = ((wid > 0) ? wsum[wid - 1] : 0) + incl - cntk;  // exclusive prefix

  float4 rst, mmk;
  float* rp = &rst.x;
  float* mp = &mmk.x;
#pragma unroll
  for (int q = 0; q < 4; ++q) {
    const int j = base + q;
    int r;
    if (c4[q]) {
      r = run;
      keep_idx[b * LL + run] = j;
      out_unmask[(size_t)b * LL + run] = (float)svA[q];
      run++;
    } else {
      r = r4[q];
    }
    rp[q] = (float)r;
    mp[q] = (r >= lk && r < eff) ? 1.0f : 0.0f;
  }
  *reinterpret_cast<float4*>(out_restore + (size_t)b * LL + base) = rst;
  *reinterpret_cast<float4*>(out_mae + (size_t)b * LL + base) = mmk;

  for (int p = tid; p < LL; p += 1024)
    if (p >= lk) out_unmask[(size_t)b * LL + p] = -1.0f;
  if (tid == 0) lk_arr[b] = lk;
}

// ---------------- proj: MFMA bf16 GEMM, 32 tokens x 256 h x K=512 per block ----------------
// grid.x = PROJ_TILES (34): only tokens 0..1087 — beyond that out0 is statically
// zero and filled in launch 1 (lk <= 1035 always).
__global__ __launch_bounds__(256) void proj_kernel(
    const float* __restrict__ patches, const unsigned short* __restrict__ Wbf,
    const float* __restrict__ bias, const float* __restrict__ pos,
    const float* __restrict__ fs_emb, const int* __restrict__ keep_idx,
    const int* __restrict__ lk_arr, float* __restrict__ out0) {
  const int tile = blockIdx.x, b = blockIdx.y, tid = threadIdx.x;
  const int p0 = tile * MT;
  int lk = lk_arr[b];
  lk = lk < 0 ? 0 : (lk > LL ? LL : lk);
  float* outB = out0 + ((size_t)b * LL + p0) * HH;
  int nt = lk - p0;
  nt = nt > MT ? MT : nt;

  if (nt <= 0) {  // pure zero-fill tile
    float4 z = make_float4(0.f, 0.f, 0.f, 0.f);
    float4* o4 = reinterpret_cast<float4*>(outB);
#pragma unroll
    for (int i = 0; i < MT * HH / 4 / 256; ++i)
      o4[i * 256 + tid] = z;
    return;
  }

  __shared__ __align__(16) unsigned short pA[MT * 520];  // [t][k] bf16, stride 520
  __shared__ int idxs[MT];
  if (tid < MT) idxs[tid] = (tid < nt) ? (keep_idx[b * LL + p0 + tid] & (LL - 1)) : 0;
  __syncthreads();

  {  // stage gathered patch rows as bf16: 8 threads per row, 64 k each
    const int r = tid >> 3, kc = (tid & 7) * 64;
    const float* prow = patches + ((size_t)b * LL + (size_t)idxs[r]) * PDIM + kc;
#pragma unroll
    for (int i = 0; i < 16; ++i) {
      float4 v = reinterpret_cast<const float4*>(prow)[i];
      ushort4 u = make_ushort4(f2bf(v.x), f2bf(v.y), f2bf(v.z), f2bf(v.w));
      *reinterpret_cast<ushort4*>(&pA[r * 520 + kc + i * 4]) = u;
    }
  }
  __syncthreads();

  const int lane = tid & 63, w = tid >> 6;
  const int li = lane & 15, q = lane >> 4;
  f32x4 zero4 = {0.f, 0.f, 0.f, 0.f};
  f32x4 acc[2][4];
#pragma unroll
  for (int m = 0; m < 2; ++m)
#pragma unroll
    for (int n = 0; n < 4; ++n) acc[m][n] = zero4;

#pragma unroll 2
  for (int k0 = 0; k0 < PDIM; k0 += 32) {
    bf16x8 a0 = *reinterpret_cast<const bf16x8*>(&pA[li * 520 + k0 + q * 8]);
    bf16x8 a1 = *reinterpret_cast<const bf16x8*>(&pA[(16 + li) * 520 + k0 + q * 8]);
#pragma unroll
    for (int n = 0; n < 4; ++n) {
      bf16x8 bf = *reinterpret_cast<const bf16x8*>(
          &Wbf[(size_t)(w * 64 + n * 16 + li) * PDIM + k0 + q * 8]);
      acc[0][n] = __builtin_amdgcn_mfma_f32_16x16x32_bf16(a0, bf, acc[0][n], 0, 0, 0);
      acc[1][n] = __builtin_amdgcn_mfma_f32_16x16x32_bf16(a1, bf, acc[1][n], 0, 0, 0);
    }
  }

  // epilogue: D[row=q*4+r][col=li] (+ bias + pos[idx] + fs_emb), rows >= lk -> 0
#pragma unroll
  for (int m = 0; m < 2; ++m) {
#pragma unroll
    for (int n = 0; n < 4; ++n) {
      const int col = w * 64 + n * 16 + li;
      const float bv = bias[col] + fs_emb[b * HH + col];
#pragma unroll
      for (int rr = 0; rr < 4; ++rr) {
        const int trow = m * 16 + q * 4 + rr;
        float val = 0.f;
        if (p0 + trow < lk)
          val = acc[m][n][rr] + bv + pos[(size_t)idxs[trow] * HH + col];
        outB[(size_t)trow * HH + col] = val;
      }
    }
  }
}

extern "C" void kernel_launch(void* const* d_in, const int* in_sizes, int n_in,
                              void* d_out, int out_size, void* d_ws, size_t ws_size,
                              hipStream_t stream) {
  const float* patches = (const float*)d_in[0];
  const int* sample_ids = (const int*)d_in[1];
  const int* eff = (const int*)d_in[2];
  const float* noise = (const float*)d_in[3];
  const float* fs = (const float*)d_in[4];
  const float* W = (const float*)d_in[5];
  const float* bias = (const float*)d_in[6];
  const float* pos = (const float*)d_in[7];
  const float* w1 = (const float*)d_in[8];
  const float* b1 = (const float*)d_in[9];
  const float* w2 = (const float*)d_in[10];
  const float* b2 = (const float*)d_in[11];

  float* out0 = (float*)d_out;                            // seq_unmasked fp32 [16,4096,256]
  float* out_mae = out0 + (size_t)BB * LL * HH;           // mae_mask   [16,4096]
  float* out_restore = out_mae + (size_t)BB * LL;         // ids_restore[16,4096]
  float* out_unmask = out_restore + (size_t)BB * LL;      // unmask_ids [16,4096]

  char* ws = (char*)d_ws;
  unsigned short* Wbf = (unsigned short*)ws;     // 262144 B (bf16 [256][512])
  float* fs_emb = (float*)(ws + 262144);         // 16384 B
  int* keep_idx = (int*)(ws + 278528);           // 262144 B
  int* lk_arr = (int*)(ws + 540672);             // 64 B
  if (ws_size < 540736) return;

  // launch 1: 16 sort blocks + 128 W-convert + 16 fs-MLP + 512 static zero-fill
  sort_prep_kernel<<<160 + FILL_BLOCKS, 1024, 0, stream>>>(
      sample_ids, eff, noise, out_mae, out_restore, out_unmask, keep_idx,
      lk_arr, W, Wbf, fs, w1, b1, w2, b2, fs_emb, out0);
  // launch 2: projection + epilogue over tokens 0..1087 only
  proj_kernel<<<dim3(PROJ_TILES, BB), 256, 0, stream>>>(patches, Wbf, bias, pos,
                                                        fs_emb, keep_idx, lk_arr,
                                                        out0);
}

// Round 3
// 259.569 us; speedup vs baseline: 1.1974x; 1.0332x over previous
//
#include <hip/hip_runtime.h>
#include <hip/hip_bf16.h>

#define BB 16
#define LL 4096
#define PDIM 512
#define HH 256
#define HALFD 128
#define MT 32      // tokens per proj block
#define NBUCK 257  // bucket 0 = exact-zero keys (prefix tokens); 1..256 = floor(noise*256)
// lk = 2*ns + (eff-2*ns)>>2 with eff<=4095, ns<=8  =>  lk <= 1035 < 1088.
// Tokens >= 1088 (tiles >= 34) of out0 are statically zero -> filled in launch 1.
#define PROJ_TILES 34
#define FILL_BLOCKS 512  // 32 per batch row

typedef short bf16x8 __attribute__((ext_vector_type(8)));   // 8 bf16 in 4 VGPRs
typedef float f32x4 __attribute__((ext_vector_type(4)));

__device__ __forceinline__ unsigned short f2bf(float f) {
  unsigned x = __float_as_uint(f);
  unsigned r = (x + 0x7FFFu + ((x >> 16) & 1u)) >> 16;
  return (unsigned short)r;
}

// ---------------- fused launch 1:
//   blocks   0..15  : per-row bucket-rank + finalize
//   blocks  16..143 : W -> bf16
//   blocks 144..159 : fs MLP
//   blocks 160..671 : static zero-fill of out0 tokens 1088..4095 (overlaps sort)
__global__ __launch_bounds__(1024) void sort_prep_kernel(
    const int* __restrict__ sample_ids, const int* __restrict__ eff_lens,
    const float* __restrict__ noise, float* __restrict__ out_mae,
    float* __restrict__ out_restore, float* __restrict__ out_unmask,
    int* __restrict__ keep_idx, int* __restrict__ lk_arr,
    const float* __restrict__ W, unsigned short* __restrict__ Wbf,
    const float* __restrict__ fs, const float* __restrict__ w1,
    const float* __restrict__ b1, const float* __restrict__ w2,
    const float* __restrict__ b2, float* __restrict__ fs_emb,
    float* __restrict__ out0) {
  __shared__ __align__(16) unsigned long long store[LL];  // 32 KB bucketed keys
  __shared__ int hist[NBUCK], cnt[NBUCK], bstart[NBUCK], bcur[NBUCK];
  __shared__ int wsum[16];
  __shared__ int lksh;
  __shared__ float tf[HH];
  __shared__ float hidv[HH];

  const int tid = threadIdx.x;

  if (blockIdx.x >= 160) {
    // static zero-fill: tokens 1088..4095 of every row are always beyond len_keep
    const int fb = blockIdx.x - 160;  // 0..511
    const int row = fb >> 5;          // 0..15
    const int chunk = fb & 31;        // 0..31
    float4* dst = reinterpret_cast<float4*>(out0 + ((size_t)row * LL + 1088) * HH);
    const int start = chunk * 6016;   // 32 * 6016 = (4096-1088)*256/4 per row
    const float4 z = make_float4(0.f, 0.f, 0.f, 0.f);
#pragma unroll
    for (int k = 0; k < 6; ++k) {
      const int i = k * 1024 + tid;
      if (i < 6016) dst[start + i] = z;
    }
    return;
  }

  if (blockIdx.x >= 16) {
    const int blk = blockIdx.x - 16;
    if (blk < 128) {  // W -> bf16: 128 blocks x 1024 = 131072 elements
      const int idx = blk * 1024 + tid;
      Wbf[idx] = f2bf(W[idx]);
      return;
    }
    // fs MLP: one block per batch row, first 256 threads active
    const int b = blk - 128, h = tid;
    const float fv = fs[b];
    if (h < HH) {
      int i = h & (HALFD - 1);
      float freq = expf(-9.210340371976184f * (float)i / 128.0f);
      float arg = fv * freq;
      tf[h] = (h < HALFD) ? cosf(arg) : sinf(arg);
    }
    __syncthreads();
    if (h < HH) {
      float acc = b1[h];
      const float* wr = w1 + (size_t)h * HH;
      for (int k = 0; k < HH; k += 4) {
        float4 w4 = *reinterpret_cast<const float4*>(&wr[k]);
        acc += tf[k] * w4.x + tf[k + 1] * w4.y + tf[k + 2] * w4.z + tf[k + 3] * w4.w;
      }
      hidv[h] = acc / (1.0f + expf(-acc));
    }
    __syncthreads();
    if (h < HH) {
      float acc2 = b2[h];
      const float* wr2 = w2 + (size_t)h * HH;
      for (int k = 0; k < HH; k += 4) {
        float4 w4 = *reinterpret_cast<const float4*>(&wr2[k]);
        acc2 += hidv[k] * w4.x + hidv[k + 1] * w4.y + hidv[k + 2] * w4.z + hidv[k + 3] * w4.w;
      }
      fs_emb[b * HH + h] = acc2;
    }
    return;
  }

  // ---------------- sort + finalize for row b ----------------
  const int b = blockIdx.x;
  const int wid = tid >> 6, lane = tid & 63;
  const int eff = eff_lens[b];
  const int* sid = sample_ids + (size_t)b * LL;
  const int base = tid * 4;

  int4 sv = *reinterpret_cast<const int4*>(&sid[base]);
  float4 nv = *reinterpret_cast<const float4*>(&noise[(size_t)b * LL + base]);
  const int sm1 = (base >= 1) ? sid[base - 1] : -1;
  const int sm2 = (base >= 2) ? sid[base - 2] : -1;
  const int svA[4] = {sv.x, sv.y, sv.z, sv.w};
  const float nvA[4] = {nv.x, nv.y, nv.z, nv.w};

  unsigned vbq[4];
  int pbq[4];
  bool invq[4];
  int segsum = 0;
#pragma unroll
  for (int q = 0; q < 4; ++q) {
    const int j = base + q;
    const int s = svA[q];
    const int sp = (q >= 1) ? svA[q - 1] : sm1;
    const int spp = (q >= 2) ? svA[q - 2] : ((q == 1) ? sm1 : sm2);
    const bool valid = j < eff;
    const bool segs = valid && (s != sp);
    const bool fst = valid && (j > 0) && (sp != spp);
    segsum += segs ? 1 : 0;
    invq[q] = !valid;
    unsigned vb = (segs || fst) ? 0u : __float_as_uint(nvA[q]);
    vbq[q] = vb;
    // monotone bucket map: exact-zero keys -> 0; else 1+floor(v*256) in [1,256]
    pbq[q] = (vb == 0u) ? 0 : (1 + (int)(__uint_as_float(vb) * 256.0f));
  }

  // histogram
  if (tid < NBUCK) hist[tid] = 0;
  __syncthreads();
#pragma unroll
  for (int q = 0; q < 4; ++q)
    if (!invq[q]) atomicAdd(&hist[pbq[q]], 1);
  __syncthreads();
  if (tid < NBUCK) cnt[tid] = hist[tid];
  __syncthreads();
  // inclusive Hillis-Steele scan over 257 buckets
  for (int off = 1; off < NBUCK; off <<= 1) {
    int v = 0;
    if (tid < NBUCK && tid >= off) v = hist[tid - off];
    __syncthreads();
    if (tid < NBUCK) hist[tid] += v;
    __syncthreads();
  }
  if (tid < NBUCK) {
    const int st = hist[tid] - cnt[tid];  // exclusive start
    bstart[tid] = st;
    bcur[tid] = st;
  }
  __syncthreads();
  // scatter valid keys into bucketed storage (order within bucket irrelevant)
#pragma unroll
  for (int q = 0; q < 4; ++q)
    if (!invq[q]) {
      const int slot = atomicAdd(&bcur[pbq[q]], 1);
      store[slot] = (((unsigned long long)vbq[q]) << 32) | (unsigned)(base + q);
    }
  __syncthreads();

  // rank: bucket start + count of strictly-smaller keys in bucket (keys unique via j)
  int r4[4];
#pragma unroll
  for (int q = 0; q < 4; ++q) {
    const int j = base + q;
    if (invq[q]) {
      r4[q] = j;
      continue;
    }
    const int pb = pbq[q];
    const int s0 = bstart[pb], c = cnt[pb];
    const unsigned long long mykey = (((unsigned long long)vbq[q]) << 32) | (unsigned)j;
    int cless = 0;
    for (int t = 0; t < c; ++t) cless += (store[s0 + t] < mykey) ? 1 : 0;
    r4[q] = s0 + cless;
  }

  // ---- ns -> len_keep ----
  int local_ns = segsum;
#pragma unroll
  for (int off = 32; off > 0; off >>= 1) local_ns += __shfl_down(local_ns, off);
  if (lane == 0) wsum[wid] = local_ns;
  __syncthreads();
  if (wid == 0) {
    int v = (lane < 16) ? wsum[lane] : 0;
#pragma unroll
    for (int off = 32; off > 0; off >>= 1) v += __shfl_down(v, off);
    if (lane == 0) {
      const int ns = v;
      lksh = 2 * ns + ((eff - 2 * ns) >> 2);  // exact trunc
    }
  }
  __syncthreads();
  const int lk = lksh;

  // ---- kept flags + exclusive prefix via shfl scan (verified structure) ----
  int c4[4], cntk = 0;
#pragma unroll
  for (int q = 0; q < 4; ++q) {
    c4[q] = (r4[q] < lk) ? 1 : 0;
    cntk += c4[q];
  }
  int incl = cntk;
#pragma unroll
  for (int off = 1; off < 64; off <<= 1) {
    int v = __shfl_up(incl, off);
    if (lane >= off) incl += v;
  }
  if (lane == 63) wsum[wid] = incl;
  __syncthreads();
  if (wid == 0) {
    int s = (lane < 16) ? wsum[lane] : 0;
#pragma unroll
    for (int off = 1; off < 16; off <<= 1) {
      int v = __shfl_up(s, off);
      if (lane >= off) s += v;
    }
    if (lane < 16) wsum[lane] = s;  // inclusive wave sums
  }
  __syncthreads();
  int run = ((wid > 0) ? wsum[wid - 1] : 0) + incl - cntk;  // exclusive prefix

  float4 rst, mmk;
  float* rp = &rst.x;
  float* mp = &mmk.x;
#pragma unroll
  for (int q = 0; q < 4; ++q) {
    const int j = base + q;
    int r;
    if (c4[q]) {
      r = run;
      keep_idx[b * LL + run] = j;
      out_unmask[(size_t)b * LL + run] = (float)svA[q];
      run++;
    } else {
      r = r4[q];
    }
    rp[q] = (float)r;
    mp[q] = (r >= lk && r < eff) ? 1.0f : 0.0f;
  }
  *reinterpret_cast<float4*>(out_restore + (size_t)b * LL + base) = rst;
  *reinterpret_cast<float4*>(out_mae + (size_t)b * LL + base) = mmk;

  for (int p = tid; p < LL; p += 1024)
    if (p >= lk) out_unmask[(size_t)b * LL + p] = -1.0f;
  if (tid == 0) lk_arr[b] = lk;
}

// ---------------- proj: MFMA bf16 GEMM, 32 tokens x 256 h x K=512 per block ----------------
// 512 threads / 8 waves per block: each wave owns 32 output columns (acc[2][2]).
// Doubles waves/CU (~17) and halves the staging latency chain vs the 256-thread
// version — proj was latency-bound (~2x its BW floor), not BW-bound.
// grid.x = PROJ_TILES (34): only tokens 0..1087 — beyond that out0 is statically
// zero and filled in launch 1 (lk <= 1035 always).
__global__ __launch_bounds__(512) void proj_kernel(
    const float* __restrict__ patches, const unsigned short* __restrict__ Wbf,
    const float* __restrict__ bias, const float* __restrict__ pos,
    const float* __restrict__ fs_emb, const int* __restrict__ keep_idx,
    const int* __restrict__ lk_arr, float* __restrict__ out0) {
  const int tile = blockIdx.x, b = blockIdx.y, tid = threadIdx.x;
  const int p0 = tile * MT;
  int lk = lk_arr[b];
  lk = lk < 0 ? 0 : (lk > LL ? LL : lk);
  float* outB = out0 + ((size_t)b * LL + p0) * HH;
  int nt = lk - p0;
  nt = nt > MT ? MT : nt;

  if (nt <= 0) {  // pure zero-fill tile: 32*256 floats = 2048 float4
    float4 z = make_float4(0.f, 0.f, 0.f, 0.f);
    float4* o4 = reinterpret_cast<float4*>(outB);
#pragma unroll
    for (int i = 0; i < 4; ++i)
      o4[i * 512 + tid] = z;
    return;
  }

  __shared__ __align__(16) unsigned short pA[MT * 520];  // [t][k] bf16, stride 520
  __shared__ int idxs[MT];
  if (tid < MT) idxs[tid] = (tid < nt) ? (keep_idx[b * LL + p0 + tid] & (LL - 1)) : 0;
  __syncthreads();

  {  // stage gathered patch rows as bf16: 16 threads per row, 32 k each
    const int r = tid >> 4, kc = (tid & 15) * 32;
    const float* prow = patches + ((size_t)b * LL + (size_t)idxs[r]) * PDIM + kc;
#pragma unroll
    for (int i = 0; i < 8; ++i) {
      float4 v = reinterpret_cast<const float4*>(prow)[i];
      ushort4 u = make_ushort4(f2bf(v.x), f2bf(v.y), f2bf(v.z), f2bf(v.w));
      *reinterpret_cast<ushort4*>(&pA[r * 520 + kc + i * 4]) = u;
    }
  }
  __syncthreads();

  const int lane = tid & 63, w = tid >> 6;  // w in 0..7
  const int li = lane & 15, q = lane >> 4;
  f32x4 zero4 = {0.f, 0.f, 0.f, 0.f};
  f32x4 acc[2][2];
#pragma unroll
  for (int m = 0; m < 2; ++m)
#pragma unroll
    for (int n = 0; n < 2; ++n) acc[m][n] = zero4;

#pragma unroll 2
  for (int k0 = 0; k0 < PDIM; k0 += 32) {
    bf16x8 a0 = *reinterpret_cast<const bf16x8*>(&pA[li * 520 + k0 + q * 8]);
    bf16x8 a1 = *reinterpret_cast<const bf16x8*>(&pA[(16 + li) * 520 + k0 + q * 8]);
#pragma unroll
    for (int n = 0; n < 2; ++n) {
      bf16x8 bf = *reinterpret_cast<const bf16x8*>(
          &Wbf[(size_t)(w * 32 + n * 16 + li) * PDIM + k0 + q * 8]);
      acc[0][n] = __builtin_amdgcn_mfma_f32_16x16x32_bf16(a0, bf, acc[0][n], 0, 0, 0);
      acc[1][n] = __builtin_amdgcn_mfma_f32_16x16x32_bf16(a1, bf, acc[1][n], 0, 0, 0);
    }
  }

  // epilogue: D[row=q*4+r][col=li] (+ bias + pos[idx] + fs_emb), rows >= lk -> 0
#pragma unroll
  for (int m = 0; m < 2; ++m) {
#pragma unroll
    for (int n = 0; n < 2; ++n) {
      const int col = w * 32 + n * 16 + li;
      const float bv = bias[col] + fs_emb[b * HH + col];
#pragma unroll
      for (int rr = 0; rr < 4; ++rr) {
        const int trow = m * 16 + q * 4 + rr;
        float val = 0.f;
        if (p0 + trow < lk)
          val = acc[m][n][rr] + bv + pos[(size_t)idxs[trow] * HH + col];
        outB[(size_t)trow * HH + col] = val;
      }
    }
  }
}

extern "C" void kernel_launch(void* const* d_in, const int* in_sizes, int n_in,
                              void* d_out, int out_size, void* d_ws, size_t ws_size,
                              hipStream_t stream) {
  const float* patches = (const float*)d_in[0];
  const int* sample_ids = (const int*)d_in[1];
  const int* eff = (const int*)d_in[2];
  const float* noise = (const float*)d_in[3];
  const float* fs = (const float*)d_in[4];
  const float* W = (const float*)d_in[5];
  const float* bias = (const float*)d_in[6];
  const float* pos = (const float*)d_in[7];
  const float* w1 = (const float*)d_in[8];
  const float* b1 = (const float*)d_in[9];
  const float* w2 = (const float*)d_in[10];
  const float* b2 = (const float*)d_in[11];

  float* out0 = (float*)d_out;                            // seq_unmasked fp32 [16,4096,256]
  float* out_mae = out0 + (size_t)BB * LL * HH;           // mae_mask   [16,4096]
  float* out_restore = out_mae + (size_t)BB * LL;         // ids_restore[16,4096]
  float* out_unmask = out_restore + (size_t)BB * LL;      // unmask_ids [16,4096]

  char* ws = (char*)d_ws;
  unsigned short* Wbf = (unsigned short*)ws;     // 262144 B (bf16 [256][512])
  float* fs_emb = (float*)(ws + 262144);         // 16384 B
  int* keep_idx = (int*)(ws + 278528);           // 262144 B
  int* lk_arr = (int*)(ws + 540672);             // 64 B
  if (ws_size < 540736) return;

  // launch 1: 16 sort blocks + 128 W-convert + 16 fs-MLP + 512 static zero-fill
  sort_prep_kernel<<<160 + FILL_BLOCKS, 1024, 0, stream>>>(
      sample_ids, eff, noise, out_mae, out_restore, out_unmask, keep_idx,
      lk_arr, W, Wbf, fs, w1, b1, w2, b2, fs_emb, out0);
  // launch 2: projection + epilogue over tokens 0..1087 only
  proj_kernel<<<dim3(PROJ_TILES, BB), 512, 0, stream>>>(patches, Wbf, bias, pos,
                                                        fs_emb, keep_idx, lk_arr,
                                                        out0);
}